// Round 2
// baseline (214.185 us; speedup 1.0000x reference)
//
#include <hip/hip_runtime.h>
#include <math.h>

// Kabsch RMSD: B=4096 rows, each row = 2048 atoms x 3 coords (float32),
// masked by n_valid = angles_length+1. Single pass: accumulate 17 raw
// moments per row (Sx[3], Sy[3], sum|x|^2, sum|y|^2, M=sum x (x) y [9]),
// then closed-form 3x3 symmetric eigensolve on C^T C for singular values.
//
//   ssq = Sxx + Syy - (|Sx|^2 + |Sy|^2)/n
//   C   = M - Sx Sy^T / n
//   tr  = S0 + S1 + sign(det C) * S2   (S = singular values of C, desc)
//   rmsd = sqrt(max(ssq - 2 tr, 0)/n + 1e-12)
//
// Layout: one 256-thread block per row. Thread t owns atoms [8t, 8t+8):
// 24 floats = 96 bytes = 6 x float4 loads per array (16B aligned).

#define NACC 17

__global__ __launch_bounds__(256) void kabsch_rmsd_kernel(
    const float* __restrict__ X,   // B x 6144 f32
    const float* __restrict__ Y,   // B x 6144 f32
    const int* __restrict__ L,     // B
    float* __restrict__ OUT)       // B f32
{
    const int row = blockIdx.x;
    const int tid = threadIdx.x;
    const int n = L[row] + 1;      // valid atom count (2..2047)

    const float4* xr = (const float4*)(X + (size_t)row * 6144) + (size_t)tid * 6;
    const float4* yr = (const float4*)(Y + (size_t)row * 6144) + (size_t)tid * 6;

    float4 x4[6], y4[6];
#pragma unroll
    for (int i = 0; i < 6; ++i) x4[i] = xr[i];
#pragma unroll
    for (int i = 0; i < 6; ++i) y4[i] = yr[i];

    float fx[24], fy[24];
#pragma unroll
    for (int i = 0; i < 6; ++i) {
        fx[4 * i + 0] = x4[i].x; fx[4 * i + 1] = x4[i].y;
        fx[4 * i + 2] = x4[i].z; fx[4 * i + 3] = x4[i].w;
        fy[4 * i + 0] = y4[i].x; fy[4 * i + 1] = y4[i].y;
        fy[4 * i + 2] = y4[i].z; fy[4 * i + 3] = y4[i].w;
    }

    // accumulators: sx0..2, sy0..2, sxx, syy, m00..m22
    float v[NACC];
#pragma unroll
    for (int k = 0; k < NACC; ++k) v[k] = 0.0f;

    const int abase = tid * 8;
#pragma unroll
    for (int a = 0; a < 8; ++a) {
        const float msk = (abase + a < n) ? 1.0f : 0.0f;
        const float x0 = fx[3 * a + 0] * msk;
        const float x1 = fx[3 * a + 1] * msk;
        const float x2 = fx[3 * a + 2] * msk;
        const float y0 = fy[3 * a + 0] * msk;
        const float y1 = fy[3 * a + 1] * msk;
        const float y2 = fy[3 * a + 2] * msk;
        v[0] += x0; v[1] += x1; v[2] += x2;
        v[3] += y0; v[4] += y1; v[5] += y2;
        v[6] += x0 * x0 + x1 * x1 + x2 * x2;
        v[7] += y0 * y0 + y1 * y1 + y2 * y2;
        v[8]  += x0 * y0; v[9]  += x0 * y1; v[10] += x0 * y2;
        v[11] += x1 * y0; v[12] += x1 * y1; v[13] += x1 * y2;
        v[14] += x2 * y0; v[15] += x2 * y1; v[16] += x2 * y2;
    }

    // wave-64 butterfly-free down-reduction
#pragma unroll
    for (int k = 0; k < NACC; ++k) {
        float t = v[k];
        t += __shfl_down(t, 32);
        t += __shfl_down(t, 16);
        t += __shfl_down(t, 8);
        t += __shfl_down(t, 4);
        t += __shfl_down(t, 2);
        t += __shfl_down(t, 1);
        v[k] = t;
    }

    __shared__ float red[4][NACC];
    const int wave = tid >> 6;
    const int lane = tid & 63;
    if (lane == 0) {
#pragma unroll
        for (int k = 0; k < NACC; ++k) red[wave][k] = v[k];
    }
    __syncthreads();

    if (tid == 0) {
        double s[NACC];
#pragma unroll
        for (int k = 0; k < NACC; ++k)
            s[k] = (double)red[0][k] + (double)red[1][k] +
                   (double)red[2][k] + (double)red[3][k];

        const double inv_n = 1.0 / (double)n;
        const double sx0 = s[0], sx1 = s[1], sx2 = s[2];
        const double sy0 = s[3], sy1 = s[4], sy2 = s[5];
        const double ssq = s[6] + s[7]
            - (sx0 * sx0 + sx1 * sx1 + sx2 * sx2) * inv_n
            - (sy0 * sy0 + sy1 * sy1 + sy2 * sy2) * inv_n;

        double C[3][3];
        C[0][0] = s[8]  - sx0 * sy0 * inv_n;
        C[0][1] = s[9]  - sx0 * sy1 * inv_n;
        C[0][2] = s[10] - sx0 * sy2 * inv_n;
        C[1][0] = s[11] - sx1 * sy0 * inv_n;
        C[1][1] = s[12] - sx1 * sy1 * inv_n;
        C[1][2] = s[13] - sx1 * sy2 * inv_n;
        C[2][0] = s[14] - sx2 * sy0 * inv_n;
        C[2][1] = s[15] - sx2 * sy1 * inv_n;
        C[2][2] = s[16] - sx2 * sy2 * inv_n;

        const double det =
              C[0][0] * (C[1][1] * C[2][2] - C[1][2] * C[2][1])
            - C[0][1] * (C[1][0] * C[2][2] - C[1][2] * C[2][0])
            + C[0][2] * (C[1][0] * C[2][1] - C[1][1] * C[2][0]);

        // A = C^T C (symmetric PSD); eigenvalues = squared singular values
        double A[3][3];
#pragma unroll
        for (int i = 0; i < 3; ++i)
#pragma unroll
            for (int j = 0; j < 3; ++j)
                A[i][j] = C[0][i] * C[0][j] + C[1][i] * C[1][j] + C[2][i] * C[2][j];

        const double q  = (A[0][0] + A[1][1] + A[2][2]) / 3.0;
        const double p1 = A[0][1] * A[0][1] + A[0][2] * A[0][2] + A[1][2] * A[1][2];
        const double a00 = A[0][0] - q, a11 = A[1][1] - q, a22 = A[2][2] - q;
        const double p2 = a00 * a00 + a11 * a11 + a22 * a22 + 2.0 * p1;
        const double p  = sqrt(p2 / 6.0);

        double e1, e2, e3;
        if (p < 1e-30) {
            e1 = e2 = e3 = q;
        } else {
            const double ip = 1.0 / p;
            const double b00 = a00 * ip, b11 = a11 * ip, b22 = a22 * ip;
            const double b01 = A[0][1] * ip, b02 = A[0][2] * ip, b12 = A[1][2] * ip;
            double r = 0.5 * (b00 * (b11 * b22 - b12 * b12)
                            - b01 * (b01 * b22 - b12 * b02)
                            + b02 * (b01 * b12 - b11 * b02));
            r = fmin(1.0, fmax(-1.0, r));
            const double phi = acos(r) / 3.0;
            e1 = q + 2.0 * p * cos(phi);
            e3 = q + 2.0 * p * cos(phi + 2.0 * M_PI / 3.0);
            e2 = 3.0 * q - e1 - e3;
        }

        const double S0 = sqrt(fmax(e1, 0.0));   // largest
        const double S1 = sqrt(fmax(e2, 0.0));
        const double S2 = sqrt(fmax(e3, 0.0));   // smallest
        const double d  = (det > 0.0) ? 1.0 : ((det < 0.0) ? -1.0 : 0.0);
        const double tr = S0 + S1 + d * S2;

        const double msd = fmax(ssq - 2.0 * tr, 0.0) * inv_n;
        OUT[row] = (float)sqrt(msd + 1e-12);
    }
}

extern "C" void kernel_launch(void* const* d_in, const int* in_sizes, int n_in,
                              void* d_out, int out_size, void* d_ws, size_t ws_size,
                              hipStream_t stream) {
    const float* X = (const float*)d_in[0];
    const float* Y = (const float*)d_in[1];
    const int* L = (const int*)d_in[2];
    float* OUT = (float*)d_out;

    const int rows = in_sizes[2];   // 4096
    kabsch_rmsd_kernel<<<rows, 256, 0, stream>>>(X, Y, L, OUT);
}